// Round 11
// baseline (68.927 us; speedup 1.0000x reference)
//
#include <hip/hip_runtime.h>

#define KK 5
#define RR 2
#define N_ 2
#define C_ 256
#define H_ 128
#define W_ 128
#define H2 256
#define W2 256
#define TH 16
#define TW 16
#define CCHUNK 8
#define PH 20
#define PW 20
#define PHPW 400
#define HW (H_*W_)
#define HW2 (H2*W2)
#define DEPTH 4              // mask prefetch ring depth
#define BLK 512

__global__ __launch_bounds__(BLK) void carafe_kernel(
    const float* __restrict__ feat,
    const float* __restrict__ masks,
    float* __restrict__ out)
{
    // Channel-group-planar: word = G*1600 + p*4 + t holds channel c0+4G+t at
    // pixel p (G in {0,1}). b128 ops land 8 words/bank = conflict floor.
    // Thread = (pixel, quad q): q picks the plane; acc is only 16 regs.
    __shared__ float patch[2 * PHPW * 4];   // 3200 words = 12800 B

    const int tid = threadIdx.x;
    const int q   = tid >> 8;          // channel-quad (wave-uniform)
    const int pp  = tid & 255;
    const int tx  = pp & 15;
    const int ty  = pp >> 4;

    // chunk-FASTEST order: concurrent blocks share one tile's masks in L2.
    const int chunk = blockIdx.x & 31;
    const int tile  = blockIdx.x >> 5;
    const int bx = tile & 7;           // W_/TW = 8
    const int by = tile >> 3;          // H_/TH = 8
    const int c0 = chunk * CCHUNK;
    const int n  = blockIdx.y;

    const int i0 = by * TH + ty;
    const int j0 = bx * TW + tx;
    const int gy0 = by * TH - RR;
    const int gx0 = bx * TW - RR;

    // ---- stage 8 channels' 20x20 halo patches: 800 float4 slots, 2 rounds ----
    const float* fbase = feat + (size_t)(n * C_ + c0) * HW;
    #pragma unroll
    for (int r = 0; r < 2; ++r) {
        const int idx = tid + r * BLK;
        if (idx < 2 * PHPW) {
            const int G  = idx / PHPW;          // 0 or 1
            const int p  = idx - G * PHPW;
            const int py = p / PW;
            const int px = p - py * PW;
            const int gy = gy0 + py;
            const int gx = gx0 + px;
            float4 v = make_float4(0.f, 0.f, 0.f, 0.f);
            if ((unsigned)gy < (unsigned)H_ && (unsigned)gx < (unsigned)W_) {
                const float* fp = fbase + (4 * G) * HW + gy * W_ + gx;
                v.x = fp[0];
                v.y = fp[HW];
                v.z = fp[2 * HW];
                v.w = fp[3 * HW];
            }
            *reinterpret_cast<float4*>(&patch[G * 1600 + p * 4]) = v;
        }
    }

    // ---- mask ring preload (latency hides under staging drain + barrier) ----
    const float* mb = masks + ((size_t)n * (KK * KK) * H2 + (size_t)(2 * i0)) * W2 + 2 * j0;
    float2 q0[DEPTH], q1[DEPTH];
    #pragma unroll
    for (int t = 0; t < DEPTH; ++t) {
        q0[t] = *reinterpret_cast<const float2*>(mb + (size_t)t * HW2);
        q1[t] = *reinterpret_cast<const float2*>(mb + (size_t)t * HW2 + W2);
    }
    __syncthreads();

    // ---- k-outer: one b128 (4 ch) + 16 FMA per k ----
    float acc[4][2][2] = {};
    const int p0 = ty * PW + tx;
    const int plane = q * 1600;

    #pragma unroll
    for (int k = 0; k < KK * KK; ++k) {
        const float2 m0 = q0[k % DEPTH];   // static index after unroll
        const float2 m1 = q1[k % DEPTH];
        if (k + DEPTH < KK * KK) {
            q0[k % DEPTH] = *reinterpret_cast<const float2*>(mb + (size_t)(k + DEPTH) * HW2);
            q1[k % DEPTH] = *reinterpret_cast<const float2*>(mb + (size_t)(k + DEPTH) * HW2 + W2);
        }
        const int dy = k / KK;
        const int dx = k - KK * dy;
        const int P  = p0 + dy * PW + dx;
        const float4 v = *reinterpret_cast<const float4*>(&patch[plane + P * 4]);

        acc[0][0][0] += v.x * m0.x;  acc[0][0][1] += v.x * m0.y;
        acc[0][1][0] += v.x * m1.x;  acc[0][1][1] += v.x * m1.y;
        acc[1][0][0] += v.y * m0.x;  acc[1][0][1] += v.y * m0.y;
        acc[1][1][0] += v.y * m1.x;  acc[1][1][1] += v.y * m1.y;
        acc[2][0][0] += v.z * m0.x;  acc[2][0][1] += v.z * m0.y;
        acc[2][1][0] += v.z * m1.x;  acc[2][1][1] += v.z * m1.y;
        acc[3][0][0] += v.w * m0.x;  acc[3][0][1] += v.w * m0.y;
        acc[3][1][0] += v.w * m1.x;  acc[3][1][1] += v.w * m1.y;
    }

    // ---- store: 4 channels x 2x2 quad, float2 rows ----
    float* ob = out + ((size_t)(n * C_ + c0 + 4 * q) * H2 + (size_t)(2 * i0)) * W2 + 2 * j0;
    #pragma unroll
    for (int t = 0; t < 4; ++t) {
        *reinterpret_cast<float2*>(ob)      = make_float2(acc[t][0][0], acc[t][0][1]);
        *reinterpret_cast<float2*>(ob + W2) = make_float2(acc[t][1][0], acc[t][1][1]);
        ob += (size_t)HW2;
    }
}

extern "C" void kernel_launch(void* const* d_in, const int* in_sizes, int n_in,
                              void* d_out, int out_size, void* d_ws, size_t ws_size,
                              hipStream_t stream) {
    const float* feat  = (const float*)d_in[0];
    const float* masks = (const float*)d_in[1];
    float* out = (float*)d_out;

    dim3 grid(32 * 64,   // chunk (fastest, 32) x tile (64)
              N_);       // batch
    carafe_kernel<<<grid, dim3(BLK), 0, stream>>>(feat, masks, out);
}

// Round 12
// 49.002 us; speedup vs baseline: 1.4066x; 1.4066x over previous
//
#include <hip/hip_runtime.h>

#define KK 5
#define RR 2
#define N_ 2
#define C_ 256
#define H_ 128
#define W_ 128
#define H2 256
#define W2 256
#define TW 32              // tile width in source pixels (wide -> 256B write runs)
#define TH 8               // tile height
#define CCHUNK 8
#define PHh 12             // TH + 4
#define PWw 36             // TW + 4
#define NPIX (PHh*PWw)     // 432 halo pixels
#define PLANE (NPIX*4)     // words per 4-channel plane
#define HW (H_*W_)
#define HW2 (H2*W2)
#define DEPTH 4            // mask prefetch ring depth

__global__ __launch_bounds__(256) void carafe_kernel(
    const float* __restrict__ feat,
    const float* __restrict__ masks,
    float* __restrict__ out)
{
    // Channel-group-planar: word = G*PLANE + p*4 + t holds channel c0+4G+t at
    // halo pixel p. Lane-adjacent b128 ops stride 4 words -> uniform 8
    // words/bank = conflict floor for stage writes and k-loop reads.
    __shared__ float patch[2 * PLANE];   // 3456 words = 13824 B

    const int tid = threadIdx.x;
    const int tx = tid & 31;           // source col within tile
    const int ty = tid >> 5;           // source row within tile (0..7)

    // XCD-bijective swizzle: bid = xcd + 8*(chunk + 32*r).
    // Each XCD owns 16 tile-n's; all 32 chunks of a tile run consecutively
    // on the SAME XCD -> tile's masks enter exactly one L2.
    const int bid   = blockIdx.x;
    const int xcd   = bid & 7;
    const int s     = bid >> 3;
    const int chunk = s & 31;
    const int tn    = xcd * 16 + (s >> 5);   // tile-n index 0..127
    const int tile  = tn & 63;
    const int n     = tn >> 6;
    const int bx    = tile & 3;              // W_/TW = 4
    const int by    = tile >> 2;             // H_/TH = 16
    const int c0    = chunk * CCHUNK;

    const int i0 = by * TH + ty;
    const int j0 = bx * TW + tx;
    const int gy0 = by * TH - RR;
    const int gx0 = bx * TW - RR;

    // ---- stage 8 channels' 12x36 halo: 864 b128 slots, 4 rounds ----
    const float* fbase = feat + (size_t)(n * C_ + c0) * HW;
    #pragma unroll
    for (int r = 0; r < 4; ++r) {
        const int idx = tid + r * 256;
        if (idx < 2 * NPIX) {
            const int G  = idx >= NPIX;
            const int p  = idx - G * NPIX;
            const int py = p / PWw;
            const int px = p - py * PWw;
            const int gy = gy0 + py;
            const int gx = gx0 + px;
            float4 v = make_float4(0.f, 0.f, 0.f, 0.f);
            if ((unsigned)gy < (unsigned)H_ && (unsigned)gx < (unsigned)W_) {
                const float* fp = fbase + (4 * G) * HW + gy * W_ + gx;
                v.x = fp[0];
                v.y = fp[HW];
                v.z = fp[2 * HW];
                v.w = fp[3 * HW];
            }
            *reinterpret_cast<float4*>(&patch[G * PLANE + p * 4]) = v;
        }
    }

    // ---- mask ring preload (latency hides under staging drain + barrier) ----
    const float* mb = masks + ((size_t)n * (KK * KK) * H2 + (size_t)(2 * i0)) * W2 + 2 * j0;
    float2 q0[DEPTH], q1[DEPTH];
    #pragma unroll
    for (int t = 0; t < DEPTH; ++t) {
        q0[t] = *reinterpret_cast<const float2*>(mb + (size_t)t * HW2);
        q1[t] = *reinterpret_cast<const float2*>(mb + (size_t)t * HW2 + W2);
    }
    __syncthreads();

    // ---- k-outer / channel-inner, depth-4 mask ring ----
    float acc[CCHUNK][2][2] = {};
    const int p0 = ty * PWw + tx;

    #pragma unroll
    for (int k = 0; k < KK * KK; ++k) {
        const float2 m0 = q0[k % DEPTH];   // static index after unroll
        const float2 m1 = q1[k % DEPTH];
        if (k + DEPTH < KK * KK) {
            q0[k % DEPTH] = *reinterpret_cast<const float2*>(mb + (size_t)(k + DEPTH) * HW2);
            q1[k % DEPTH] = *reinterpret_cast<const float2*>(mb + (size_t)(k + DEPTH) * HW2 + W2);
        }
        const int dy = k / KK;
        const int dx = k - KK * dy;
        const int P  = p0 + dy * PWw + dx;
        const float4 v0 = *reinterpret_cast<const float4*>(&patch[P * 4]);
        const float4 v1 = *reinterpret_cast<const float4*>(&patch[PLANE + P * 4]);

        acc[0][0][0] += v0.x * m0.x;  acc[0][0][1] += v0.x * m0.y;
        acc[0][1][0] += v0.x * m1.x;  acc[0][1][1] += v0.x * m1.y;
        acc[1][0][0] += v0.y * m0.x;  acc[1][0][1] += v0.y * m0.y;
        acc[1][1][0] += v0.y * m1.x;  acc[1][1][1] += v0.y * m1.y;
        acc[2][0][0] += v0.z * m0.x;  acc[2][0][1] += v0.z * m0.y;
        acc[2][1][0] += v0.z * m1.x;  acc[2][1][1] += v0.z * m1.y;
        acc[3][0][0] += v0.w * m0.x;  acc[3][0][1] += v0.w * m0.y;
        acc[3][1][0] += v0.w * m1.x;  acc[3][1][1] += v0.w * m1.y;
        acc[4][0][0] += v1.x * m0.x;  acc[4][0][1] += v1.x * m0.y;
        acc[4][1][0] += v1.x * m1.x;  acc[4][1][1] += v1.x * m1.y;
        acc[5][0][0] += v1.y * m0.x;  acc[5][0][1] += v1.y * m0.y;
        acc[5][1][0] += v1.y * m1.x;  acc[5][1][1] += v1.y * m1.y;
        acc[6][0][0] += v1.z * m0.x;  acc[6][0][1] += v1.z * m0.y;
        acc[6][1][0] += v1.z * m1.x;  acc[6][1][1] += v1.z * m1.y;
        acc[7][0][0] += v1.w * m0.x;  acc[7][0][1] += v1.w * m0.y;
        acc[7][1][0] += v1.w * m1.x;  acc[7][1][1] += v1.w * m1.y;
    }

    // ---- store: 8 channels x 2x2 quad; wave rows are 256B contiguous ----
    float* ob = out + ((size_t)(n * C_ + c0) * H2 + (size_t)(2 * i0)) * W2 + 2 * j0;
    #pragma unroll
    for (int c = 0; c < CCHUNK; ++c) {
        *reinterpret_cast<float2*>(ob)      = make_float2(acc[c][0][0], acc[c][0][1]);
        *reinterpret_cast<float2*>(ob + W2) = make_float2(acc[c][1][0], acc[c][1][1]);
        ob += (size_t)HW2;
    }
}

extern "C" void kernel_launch(void* const* d_in, const int* in_sizes, int n_in,
                              void* d_out, int out_size, void* d_ws, size_t ws_size,
                              hipStream_t stream) {
    const float* feat  = (const float*)d_in[0];
    const float* masks = (const float*)d_in[1];
    float* out = (float*)d_out;

    // 4096 blocks flat: 64 tiles x 32 chunks x 2 batch, XCD-swizzled in-kernel
    carafe_kernel<<<dim3(4096), dim3(256), 0, stream>>>(feat, masks, out);
}